// Round 1
// baseline (885.334 us; speedup 1.0000x reference)
//
#include <hip/hip_runtime.h>
#include <math.h>

#define BB 64
#define NN 4096
#define FF 128
#define KK 64
#define TILE 128
#define NT 4
#define NSTEP 4

__device__ __forceinline__ float dot4acc(float4 a, float4 b, float s) {
    return fmaf(a.w, b.w, fmaf(a.z, b.z, fmaf(a.y, b.y, fmaf(a.x, b.x, s))));
}

// ---------- stats: partial sums of emb and emb^2 over n (masked) ----------
__global__ void k_stats_part(const float* __restrict__ emb, const int* __restrict__ nbv,
                             float* __restrict__ spart) {
    int b = blockIdx.y, s = blockIdx.x;
    int nb = nbv[b];
    int t = threadIdx.x;
    int c = t & 31, rr = t >> 5;
    int n0 = s * 512;
    int n1 = min(n0 + 512, nb);
    float4 s1 = {0,0,0,0}, s2 = {0,0,0,0};
    const float4* base = (const float4*)(emb + (size_t)b * NN * FF);
    for (int n = n0 + rr; n < n1; n += 8) {
        float4 e = base[(size_t)n * 32 + c];
        s1.x += e.x; s1.y += e.y; s1.z += e.z; s1.w += e.w;
        s2.x += e.x*e.x; s2.y += e.y*e.y; s2.z += e.z*e.z; s2.w += e.w*e.w;
    }
    __shared__ __align__(16) float4 r1[8][32];
    __shared__ __align__(16) float4 r2[8][32];
    r1[rr][c] = s1; r2[rr][c] = s2;
    __syncthreads();
    if (t < 32) {
        float4 a1 = r1[0][t], a2 = r2[0][t];
        #pragma unroll
        for (int r = 1; r < 8; ++r) {
            float4 u = r1[r][t], v = r2[r][t];
            a1.x+=u.x; a1.y+=u.y; a1.z+=u.z; a1.w+=u.w;
            a2.x+=v.x; a2.y+=v.y; a2.z+=v.z; a2.w+=v.w;
        }
        ((float4*)(spart + ((size_t)(b*8+s)*2 + 0)*FF))[t] = a1;
        ((float4*)(spart + ((size_t)(b*8+s)*2 + 1)*FF))[t] = a2;
    }
}

// ---------- stats finalize: mean, rstd per (b,f) ----------
__global__ void k_stats_fin(const float* __restrict__ spart, const int* __restrict__ nbv,
                            float* __restrict__ meanp, float* __restrict__ rstdp) {
    int b = blockIdx.x, f = threadIdx.x;
    float s1 = 0.f, s2 = 0.f;
    #pragma unroll
    for (int s = 0; s < 8; ++s) {
        s1 += spart[((size_t)(b*8+s)*2 + 0)*FF + f];
        s2 += spart[((size_t)(b*8+s)*2 + 1)*FF + f];
    }
    float nb = (float)nbv[b];
    float mean = s1 / nb;
    float var = s2 / nb - mean * mean;
    meanp[b*FF + f] = mean;
    rstdp[b*FF + f] = rsqrtf(var + 1e-5f);
}

// ---------- init mu = x[:, init_idx] ----------
__global__ void k_init(const float* __restrict__ emb, const int* __restrict__ nbv,
                       const int* __restrict__ init_idx,
                       const float* __restrict__ meanp, const float* __restrict__ rstdp,
                       float* __restrict__ mu) {
    size_t i = (size_t)blockIdx.x * 256 + threadIdx.x;   // < B*K*F
    int f = (int)(i & 127);
    int k = (int)((i >> 7) & 63);
    int b = (int)(i >> 13);
    int row = init_idx[k];
    float v = 0.f;
    if (row < nbv[b]) {
        float e = emb[((size_t)b * NN + row) * FF + f];
        v = (e - meanp[b*FF + f]) * rstdp[b*FF + f];
    }
    mu[i] = v;
}

// ---------- EM step: S = x mu^T, P = normalized likelihood, partial += P^T x ----------
__global__ __launch_bounds__(512) void k_em(const float* __restrict__ emb,
                                            const int* __restrict__ nbv,
                                            const float* __restrict__ meanp,
                                            const float* __restrict__ rstdp,
                                            const float* __restrict__ mu_in,
                                            float* __restrict__ partial) {
    __shared__ __align__(16) float4 xs[TILE][32];   // x tile, slot ^= (row>>2)&7
    __shared__ __align__(16) float4 mus[KK][32];    // mu,    slot ^= (row>>2)&7
    __shared__ __align__(16) float sp[TILE][64];    // S/P,   f4-slot ^= (row>>2)&7
    __shared__ __align__(16) float mean_s[FF];
    __shared__ __align__(16) float rstd_s[FF];
    __shared__ float x2s[TILE];
    __shared__ float m2s[KK];

    int b = blockIdx.y, t0 = blockIdx.x;
    int nb = nbv[b];
    int t = threadIdx.x;
    int lane = t & 63, w = t >> 6;

    if (t < FF) mean_s[t] = meanp[b*FF + t];
    else if (t < 2*FF) rstd_s[t - FF] = rstdp[b*FF + (t - FF)];

    // stage mu + per-row |mu|^2
    {
        const float4* src = (const float4*)(mu_in + (size_t)b * KK * FF);
        #pragma unroll
        for (int j = 0; j < 4; ++j) {
            int g = t + 512 * j;           // 2048 float4s
            int row = g >> 5, c = g & 31;
            float4 v = src[g];
            mus[row][c ^ ((row >> 2) & 7)] = v;
            float q = v.x*v.x + v.y*v.y + v.z*v.z + v.w*v.w;
            q += __shfl_xor(q, 16); q += __shfl_xor(q, 8);
            q += __shfl_xor(q, 4);  q += __shfl_xor(q, 2); q += __shfl_xor(q, 1);
            if ((t & 31) == 0) m2s[row] = q;
        }
    }

    // persistent P^T x accumulators: lane owns k = 4*(lane&15)+kk, f = 16*w + 4*(lane>>4)+ff
    float4 acc0 = {0,0,0,0}, acc1 = {0,0,0,0}, acc2 = {0,0,0,0}, acc3 = {0,0,0,0};
    __syncthreads();

    int nTiles = (nb + TILE - 1) / TILE;
    for (int tt = t0; tt < nTiles; tt += NT) {
        int row0 = tt * TILE;
        // ---- stage x tile (normalize on the fly) + per-row |x|^2 ----
        {
            const float4* erow = (const float4*)(emb + ((size_t)b * NN + row0) * FF);
            #pragma unroll
            for (int j = 0; j < 8; ++j) {
                int g = t + 512 * j;       // 4096 float4s
                int r = g >> 5, c = g & 31;
                int n = row0 + r;
                float4 v = {0,0,0,0};
                if (n < nb) {
                    float4 e = erow[g];
                    float4 mn = ((float4*)mean_s)[c];
                    float4 rs = ((float4*)rstd_s)[c];
                    v.x = (e.x - mn.x) * rs.x;
                    v.y = (e.y - mn.y) * rs.y;
                    v.z = (e.z - mn.z) * rs.z;
                    v.w = (e.w - mn.w) * rs.w;
                }
                xs[r][c ^ ((r >> 2) & 7)] = v;
                float q = v.x*v.x + v.y*v.y + v.z*v.z + v.w*v.w;
                q += __shfl_xor(q, 16); q += __shfl_xor(q, 8);
                q += __shfl_xor(q, 4);  q += __shfl_xor(q, 2); q += __shfl_xor(q, 1);
                if ((t & 31) == 0) x2s[r] = q;
            }
        }
        __syncthreads();

        // ---- GEMM1: S[128][64] = x . mu^T ----
        {
            int lr = lane & 15;
            int kq = w & 3, rh = w >> 2;
            int rbase = rh * 64 + lr * 4;
            int k4 = kq * 4 + (lane >> 4);      // float4-slot of k; mu rows 4*k4..+3
            int aswz = lr & 7;                   // (row>>2)&7 for all 4 a-rows
            int bswz = k4 & 7;
            float4 s0 = {0,0,0,0}, s1 = {0,0,0,0}, s2 = {0,0,0,0}, s3 = {0,0,0,0};
            #pragma unroll 2
            for (int fc = 0; fc < 32; ++fc) {
                int as = fc ^ aswz, bs = fc ^ bswz;
                float4 a0 = xs[rbase + 0][as];
                float4 a1 = xs[rbase + 1][as];
                float4 a2 = xs[rbase + 2][as];
                float4 a3 = xs[rbase + 3][as];
                float4 b0 = mus[k4*4 + 0][bs];
                float4 b1 = mus[k4*4 + 1][bs];
                float4 b2 = mus[k4*4 + 2][bs];
                float4 b3 = mus[k4*4 + 3][bs];
                s0.x = dot4acc(a0, b0, s0.x); s0.y = dot4acc(a0, b1, s0.y);
                s0.z = dot4acc(a0, b2, s0.z); s0.w = dot4acc(a0, b3, s0.w);
                s1.x = dot4acc(a1, b0, s1.x); s1.y = dot4acc(a1, b1, s1.y);
                s1.z = dot4acc(a1, b2, s1.z); s1.w = dot4acc(a1, b3, s1.w);
                s2.x = dot4acc(a2, b0, s2.x); s2.y = dot4acc(a2, b1, s2.y);
                s2.z = dot4acc(a2, b2, s2.z); s2.w = dot4acc(a2, b3, s2.w);
                s3.x = dot4acc(a3, b0, s3.x); s3.y = dot4acc(a3, b1, s3.y);
                s3.z = dot4acc(a3, b2, s3.z); s3.w = dot4acc(a3, b3, s3.w);
            }
            ((float4*)&sp[rbase + 0][0])[k4 ^ aswz] = s0;
            ((float4*)&sp[rbase + 1][0])[k4 ^ aswz] = s1;
            ((float4*)&sp[rbase + 2][0])[k4 ^ aswz] = s2;
            ((float4*)&sp[rbase + 3][0])[k4 ^ aswz] = s3;
        }
        __syncthreads();

        // ---- softmax-like normalize: P = (exp(-.5*norm)+1e-20)/(rowsum+1e-40) ----
        for (int i = 0; i < 16; ++i) {
            int r = w * 16 + i;
            int swz = (r >> 2) & 7;
            int col = (((lane >> 2) ^ swz) << 2) | (lane & 3);
            float s = sp[r][col];
            float norm = x2s[r] - 2.f * s + m2s[lane];
            float lik = expf(-0.5f * norm) + 1e-20f;
            float tot = lik;
            tot += __shfl_xor(tot, 1);  tot += __shfl_xor(tot, 2);
            tot += __shfl_xor(tot, 4);  tot += __shfl_xor(tot, 8);
            tot += __shfl_xor(tot, 16); tot += __shfl_xor(tot, 32);
            sp[r][col] = lik / (tot + 1e-40f);
        }
        __syncthreads();

        // ---- GEMM2: partial_mu[64][128] += P^T . x ----
        {
            int kg = lane & 15, fg = lane >> 4;
            int fslot = w * 4 + fg;
            #pragma unroll 4
            for (int n = 0; n < TILE; ++n) {
                int swz = (n >> 2) & 7;
                float4 p4 = *(const float4*)&sp[n][(kg ^ swz) << 2];
                float4 x4 = xs[n][fslot ^ swz];
                acc0.x = fmaf(p4.x, x4.x, acc0.x); acc0.y = fmaf(p4.x, x4.y, acc0.y);
                acc0.z = fmaf(p4.x, x4.z, acc0.z); acc0.w = fmaf(p4.x, x4.w, acc0.w);
                acc1.x = fmaf(p4.y, x4.x, acc1.x); acc1.y = fmaf(p4.y, x4.y, acc1.y);
                acc1.z = fmaf(p4.y, x4.z, acc1.z); acc1.w = fmaf(p4.y, x4.w, acc1.w);
                acc2.x = fmaf(p4.z, x4.x, acc2.x); acc2.y = fmaf(p4.z, x4.y, acc2.y);
                acc2.z = fmaf(p4.z, x4.z, acc2.z); acc2.w = fmaf(p4.z, x4.w, acc2.w);
                acc3.x = fmaf(p4.w, x4.x, acc3.x); acc3.y = fmaf(p4.w, x4.y, acc3.y);
                acc3.z = fmaf(p4.w, x4.z, acc3.z); acc3.w = fmaf(p4.w, x4.w, acc3.w);
            }
        }
        __syncthreads();   // protect xs/sp before next tile's staging
    }

    // write partials: k = 4*(lane&15)+kk, f = 16*w + 4*(lane>>4)
    {
        int kg = lane & 15, fg = lane >> 4;
        float* pp = partial + (((size_t)t0 * BB + b) * KK) * FF;
        int f = w * 16 + fg * 4;
        *((float4*)(pp + (size_t)(kg*4 + 0) * FF + f)) = acc0;
        *((float4*)(pp + (size_t)(kg*4 + 1) * FF + f)) = acc1;
        *((float4*)(pp + (size_t)(kg*4 + 2) * FF + f)) = acc2;
        *((float4*)(pp + (size_t)(kg*4 + 3) * FF + f)) = acc3;
    }
}

// ---------- reduce NT partials -> mu_out ----------
__global__ void k_reduce(const float* __restrict__ partial, float* __restrict__ mu_out) {
    size_t i = (size_t)blockIdx.x * 256 + threadIdx.x;   // < B*K*F
    float s = 0.f;
    #pragma unroll
    for (int tpart = 0; tpart < NT; ++tpart)
        s += partial[(size_t)tpart * BB * KK * FF + i];
    mu_out[i] = s;
}

// ---------- final: out[b] = sigmoid(mean_k(mu . w) + bias) ----------
__global__ void k_final(const float* __restrict__ mu, const float* __restrict__ fc_w,
                        const float* __restrict__ fc_b, float* __restrict__ out) {
    int b = blockIdx.x, t = threadIdx.x;     // 256 threads
    int k = t >> 2, q = t & 3;
    const float* m = mu + ((size_t)b * KK + k) * FF + q * 32;
    const float* wv = fc_w + q * 32;
    float s = 0.f;
    #pragma unroll
    for (int i = 0; i < 32; ++i) s = fmaf(m[i], wv[i], s);
    s += __shfl_xor(s, 1); s += __shfl_xor(s, 2);
    __shared__ float kd[KK];
    if (q == 0) kd[k] = s;
    __syncthreads();
    if (t < 64) {
        float v = kd[t];
        v += __shfl_xor(v, 1);  v += __shfl_xor(v, 2);  v += __shfl_xor(v, 4);
        v += __shfl_xor(v, 8);  v += __shfl_xor(v, 16); v += __shfl_xor(v, 32);
        if (t == 0) {
            float o = v / (float)KK + fc_b[0];
            out[b] = 1.f / (1.f + expf(-o));
        }
    }
}

extern "C" void kernel_launch(void* const* d_in, const int* in_sizes, int n_in,
                              void* d_out, int out_size, void* d_ws, size_t ws_size,
                              hipStream_t stream) {
    const float* emb      = (const float*)d_in[0];
    // d_in[1] = mask (float) — equivalent to arange(N) < batch_nb_nodes; unused
    const float* fc_w     = (const float*)d_in[2];
    const float* fc_b     = (const float*)d_in[3];
    const int*   nbv      = (const int*)d_in[4];
    const int*   init_idx = (const int*)d_in[5];
    float* out = (float*)d_out;

    float* wsf   = (float*)d_ws;
    float* meanp = wsf;                         // B*F
    float* rstdp = meanp + BB*FF;               // B*F
    float* spart = rstdp + BB*FF;               // B*8*2*F
    float* muA   = spart + (size_t)BB*8*2*FF;   // B*K*F
    float* muB   = muA + (size_t)BB*KK*FF;      // B*K*F
    float* part  = muB + (size_t)BB*KK*FF;      // NT*B*K*F

    k_stats_part<<<dim3(8, BB), 256, 0, stream>>>(emb, nbv, spart);
    k_stats_fin<<<BB, 128, 0, stream>>>(spart, nbv, meanp, rstdp);
    k_init<<<(BB*KK*FF)/256, 256, 0, stream>>>(emb, nbv, init_idx, meanp, rstdp, muA);

    for (int step = 0; step < NSTEP; ++step) {
        const float* mu_in = (step & 1) ? muB : muA;
        float* mu_out      = (step & 1) ? muA : muB;
        k_em<<<dim3(NT, BB), 512, 0, stream>>>(emb, nbv, meanp, rstdp, mu_in, part);
        k_reduce<<<(BB*KK*FF)/256, 256, 0, stream>>>(part, mu_out);
    }
    // after step 3 (odd), result is in muA
    k_final<<<BB, 256, 0, stream>>>(muA, fc_w, fc_b, out);
}